// Round 9
// baseline (231.048 us; speedup 1.0000x reference)
//
#include <hip/hip_runtime.h>

// VectorQuantizer on MI355X — np-fp32-exact (absmax 0.0). bf16-split MFMA
// approx scores + candidate-exact-compare (np chain) for near-tie rows.
//
// R11: T4 counted-vmcnt double-buffer pipeline in argmin. R6/R9/R10 bracketed
// the m97-structure wall (~65us, MfmaUtil 32%: drain-before-barrier exposes
// L3/HBM staging latency; no pipe saturated). Fix per m218 (counted-vs-drain0
// = +38-73%): double-buffer LDS; per dc wait `vmcnt(8)` (dc's 8 oldest gl16
// only; dc+1's stay IN FLIGHT across the barrier) + raw s_barrier (NOT
// __syncthreads — that re-drains vmcnt(0), which is exactly R6's mistake);
// stage dc+2 after the read-done barrier. Prefetch distance = full dc phase
// (~2K cy) covers far-memory latency. s_setprio(1) around MFMA cluster (T5).
// 69.6KB LDS -> 2 blocks/CU (m201: 8 waves/CU suffices with this discipline).
// Swizzle/decode/stores/numerics unchanged -> bit-identical, absmax 0.0.
//
// Decision architecture (np-exact guarantees):
//   argmin (MFMA): per-(row,128-code-split) top-4 VALUES + top-3 INDICES
//   combine:       b1 = global best; any split's v4 within TAU of b1 -> listB;
//                  else collect recorded (v,i) with v-b1<TAU: 1 -> decided,
//                  else listA
//   resolve:       listA: np-exact chain per candidate; listB: full rescan
//
// ws layout (float units):
//   0 sumsq | 1 nA | 2 nB | 64 counts[1024] | 1088 ee[1024] | 2112 xx[32768]
//   34880 pv0 | 297024 pv1 | 559168 pv2 | 821312 pv3            [8*32768 ea]
//   1083456 pi0 | 1345600 pi1 | 1607744 pi2                     [8*32768 ea]
//   1869888 listA[16384*32 int] | 2394176 listB[8192 int]
//   2402368 EhT ushort[262144] | 2533440 ElT ushort[262144]
//   2664512 fidx[32768]
//   2697280 XhT ushort[8*32768*32] | 6891584 XlT ushort[8*32768*32]
//   -> ~44.4 MB total.

#define NROWS 32768
#define CAPA 16384
#define CAPB 8192
#define GAP_TAU 1e-4f

typedef __attribute__((ext_vector_type(8))) short short8;
typedef __attribute__((ext_vector_type(8))) unsigned short ushort8;
typedef __attribute__((ext_vector_type(4))) float f32x4;

// Top-4 values, top-3 indices, value-sorted ascending.
struct Top4 { float v0, v1, v2, v3; int i0, i1, i2; };

__device__ __forceinline__ void top4_init(Top4& t) {
    t.v0 = t.v1 = t.v2 = t.v3 = 3.4e38f;
    t.i0 = t.i1 = t.i2 = 0x7fffffff;
}
__device__ __forceinline__ void top4_insert(Top4& t, float cv, int ci) {
    if (cv < t.v3) {
        if (cv < t.v2) {
            t.v3 = t.v2;
            if (cv < t.v1) {
                t.v2 = t.v1; t.i2 = t.i1;
                if (cv < t.v0) { t.v1 = t.v0; t.i1 = t.i0; t.v0 = cv; t.i0 = ci; }
                else           { t.v1 = cv; t.i1 = ci; }
            } else { t.v2 = cv; t.i2 = ci; }
        } else { t.v3 = cv; }
    }
}
__device__ __forceinline__ void top4_merge(Top4& t, const Top4& o) {
    top4_insert(t, o.v0, o.i0);
    top4_insert(t, o.v1, o.i1);
    top4_insert(t, o.v2, o.i2);
    t.v3 = fminf(t.v3, o.v3);
}

__device__ __forceinline__ unsigned short bf16_rne(float v) {
    unsigned int u = __float_as_uint(v);
    return (unsigned short)((u + 0x7fffu + ((u >> 16) & 1u)) >> 16);
}
__device__ __forceinline__ float bf16_to_f(unsigned short h) {
    return __uint_as_float(((unsigned int)h) << 16);
}

// async global -> LDS, 16B per lane. LDS dest = wave-uniform base + lane*16.
__device__ __forceinline__ void gl16(const void* g, void* l) {
    __builtin_amdgcn_global_load_lds(
        (const __attribute__((address_space(1))) unsigned int*)g,
        (__attribute__((address_space(3))) unsigned int*)l, 16, 0, 0);
}

// numpy pairwise sum of squares over 256: pw128+pw128, 8-lane accumulators.
template <int STRIDE>
__device__ __forceinline__ float np_sumsq256(const float* __restrict__ p) {
    float half[2];
#pragma unroll
    for (int h = 0; h < 2; ++h) {
        float r[8];
#pragma unroll
        for (int j = 0; j < 8; ++j) {
            const float v = p[(size_t)(h * 128 + j) * STRIDE];
            r[j] = __fmul_rn(v, v);
        }
        for (int i = 8; i < 128; i += 8) {
#pragma unroll
            for (int j = 0; j < 8; ++j) {
                const float v = p[(size_t)(h * 128 + i + j) * STRIDE];
                r[j] = __fadd_rn(r[j], __fmul_rn(v, v));
            }
        }
        half[h] = __fadd_rn(__fadd_rn(__fadd_rn(r[0], r[1]), __fadd_rn(r[2], r[3])),
                            __fadd_rn(__fadd_rn(r[4], r[5]), __fadd_rn(r[6], r[7])));
    }
    return __fadd_rn(half[0], half[1]);
}

// blocks 0..3: ee; 4..259: E -> bf16 h/l tiled [dc][code][32] (slot-swizzled);
// 260..387: fused xx + X trunc-split tiled [dc][n][32] (slot-swizzled);
// block 388: zero scalars+counts (replaces hipMemsetAsync).
__global__ void prep_kernel(const float* __restrict__ emb, const float* __restrict__ x,
                            float* __restrict__ ee, float* __restrict__ xx,
                            unsigned short* __restrict__ EhT, unsigned short* __restrict__ ElT,
                            unsigned short* __restrict__ XhT, unsigned short* __restrict__ XlT,
                            float* __restrict__ wzero) {
    if (blockIdx.x >= 388) {
        for (int i = threadIdx.x; i < 1088; i += 256) wzero[i] = 0.f;
        return;
    }
    if (blockIdx.x < 4) {
        const int k = blockIdx.x * 256 + threadIdx.x;
        ee[k] = np_sumsq256<1>(emb + (size_t)k * 256);
        return;
    }
    if (blockIdx.x >= 260) {
        // One thread per pixel n: np-exact xx (identical order to
        // np_sumsq256<1024>) + truncation hi/lo split, per-dc-chunk tiles.
        const int n = (blockIdx.x - 260) * 256 + threadIdx.x;
        const int b = n >> 10, p = n & 1023;
        const float* xb = x + (size_t)b * 262144 + p;
        const int kk = (n >> 1) & 3;               // row-in-tile swizzle key
        float r[8];
        float half0 = 0.f, half1 = 0.f;
        for (int dc = 0; dc < 8; ++dc) {
            float v[32];
#pragma unroll
            for (int j = 0; j < 32; ++j)
                v[j] = xb[(size_t)(dc * 32 + j) * 1024];
            // np pairwise accumulation (d-sequential in 8-lane groups)
            if ((dc & 3) == 0) {
#pragma unroll
                for (int j = 0; j < 8; ++j) r[j] = __fmul_rn(v[j], v[j]);
#pragma unroll
                for (int g = 1; g < 4; ++g)
#pragma unroll
                    for (int j = 0; j < 8; ++j)
                        r[j] = __fadd_rn(r[j], __fmul_rn(v[g * 8 + j], v[g * 8 + j]));
            } else {
#pragma unroll
                for (int g = 0; g < 4; ++g)
#pragma unroll
                    for (int j = 0; j < 8; ++j)
                        r[j] = __fadd_rn(r[j], __fmul_rn(v[g * 8 + j], v[g * 8 + j]));
            }
            if ((dc & 3) == 3) {
                const float s = __fadd_rn(
                    __fadd_rn(__fadd_rn(r[0], r[1]), __fadd_rn(r[2], r[3])),
                    __fadd_rn(__fadd_rn(r[4], r[5]), __fadd_rn(r[6], r[7])));
                if (dc == 3) half0 = s; else half1 = s;
            }
            // truncation split: h = high16(v); l = high16(v - bf16(h)).
            // Store slot g at physical slot g^kk (XOR bank swizzle).
            const size_t xrow = ((size_t)dc * NROWS + n) * 32;
#pragma unroll
            for (int g = 0; g < 4; ++g) {
                ushort8 H, L;
#pragma unroll
                for (int j = 0; j < 8; ++j) {
                    const float vv = v[g * 8 + j];
                    const unsigned int u = __float_as_uint(vv);
                    H[j] = (unsigned short)(u >> 16);
                    const float rr = vv - __uint_as_float(u & 0xFFFF0000u);
                    L[j] = (unsigned short)(__float_as_uint(rr) >> 16);
                }
                *(ushort8*)(XhT + xrow + (g ^ kk) * 8) = H;
                *(ushort8*)(XlT + xrow + (g ^ kk) * 8) = L;
            }
        }
        xx[n] = __fadd_rn(half0, half1);
        return;
    }
    // E split (RNE h + RNE residual), tiled [dc][code][32], slot-swizzled.
    const int eid = (blockIdx.x - 4) * 256 + threadIdx.x;   // 0..65535
    const int code = eid >> 6;
    const int d0 = (eid & 63) * 4;
    float4 v = *(const float4*)(emb + (size_t)code * 256 + d0);
    const float vv[4] = {v.x, v.y, v.z, v.w};
    unsigned short h[4], l[4];
#pragma unroll
    for (int i = 0; i < 4; ++i) {
        h[i] = bf16_rne(vv[i]);
        l[i] = bf16_rne(vv[i] - bf16_to_f(h[i]));
    }
    const int kk = (code >> 1) & 3;
    const int slot = (d0 & 31) >> 3;          // 16B slot in 64B row
    const int within = (d0 & 31) & 7;         // ushort offset in slot
    const size_t o = ((size_t)(d0 >> 5) * 1024 + code) * 32
                   + (size_t)((slot ^ kk) * 8 + within);
    *(ushort4*)(EhT + o) = make_ushort4(h[0], h[1], h[2], h[3]);
    *(ushort4*)(ElT + o) = make_ushort4(l[0], l[1], l[2], l[3]);
}

// MFMA argmin: 128 codes x 128 rows per block; grid 2048. R7 decode.
// T4 counted-vmcnt double-buffer: prologue stages dc0+dc1; per dc wait
// vmcnt(8) (keep next stage's 8 gl16 in flight across raw s_barrier),
// compute (setprio-wrapped), barrier, stage dc+2 into freed buffer.
// 4 waves: w>>1 code-half, w&1 n-half; 4x4 tiles of 16x16x32.
__global__ __launch_bounds__(256, 2)
void mfma_argmin_kernel(const unsigned short* __restrict__ XhT, const unsigned short* __restrict__ XlT,
                        const unsigned short* __restrict__ EhT, const unsigned short* __restrict__ ElT,
                        const float* __restrict__ ee, const float* __restrict__ xx,
                        float* __restrict__ pv0, float* __restrict__ pv1,
                        float* __restrict__ pv2, float* __restrict__ pv3,
                        int* __restrict__ pi0, int* __restrict__ pi1, int* __restrict__ pi2) {
    __shared__ __attribute__((aligned(16))) unsigned short Eh_s[2][4096];
    __shared__ __attribute__((aligned(16))) unsigned short El_s[2][4096];
    __shared__ __attribute__((aligned(16))) unsigned short Xh_s[2][4096];
    __shared__ __attribute__((aligned(16))) unsigned short Xl_s[2][4096];
    __shared__ float eeLds[128];
    __shared__ float mV0[128], mV1[128], mV2[128], mV3[128];
    __shared__ int   mI0[128], mI1[128], mI2[128];

    const int t = threadIdx.x;
    const int w = t >> 6, lane = t & 63;
    const int lane15 = lane & 15, quad = lane >> 4;
    const int nblk = blockIdx.x & 255, cblk = blockIdx.x >> 8;
    const int n0 = nblk * 128, c0 = cblk * 128;

    if (t < 128) eeLds[t] = ee[c0 + t];

    // Hoisted fragment LDS offsets. Swizzled slot = quad ^ ((lane15>>1)&3)
    // (row bases are multiples of 16 -> key depends only on lane15).
    const int fslot = (quad ^ ((lane15 >> 1) & 3)) * 8;
    int eoffs[4], xoffs[4];
#pragma unroll
    for (int i = 0; i < 4; ++i)
        eoffs[i] = ((w >> 1) * 64 + i * 16 + lane15) * 32 + fslot;
#pragma unroll
    for (int j = 0; j < 4; ++j)
        xoffs[j] = ((w & 1) * 64 + j * 16 + lane15) * 32 + fslot;

    f32x4 acc[4][4];
#pragma unroll
    for (int i = 0; i < 4; ++i)
#pragma unroll
        for (int j = 0; j < 4; ++j) acc[i][j] = (f32x4){0.f, 0.f, 0.f, 0.f};

    auto STAGE = [&](int dc, int bb) {
        const size_t xoff = ((size_t)dc * NROWS + n0) * 32;
        const size_t eoff = ((size_t)dc * 1024 + c0) * 32;
#pragma unroll
        for (int k = 0; k < 2; ++k) {
            const int id = k * 256 + t;               // 16B chunk index
            const int ldso = (k * 256 + w * 64) * 8;  // wave-uniform ushort off
            gl16(XhT + xoff + (size_t)id * 8, &Xh_s[bb][ldso]);
            gl16(XlT + xoff + (size_t)id * 8, &Xl_s[bb][ldso]);
            gl16(EhT + eoff + (size_t)id * 8, &Eh_s[bb][ldso]);
            gl16(ElT + eoff + (size_t)id * 8, &El_s[bb][ldso]);
        }
    };

    STAGE(0, 0);     // 8 gl16/wave in flight
    STAGE(1, 1);     // 16 in flight

#pragma unroll
    for (int dc = 0; dc < 8; ++dc) {
        const int bb = dc & 1;
        // Counted wait: this dc's 8 oldest gl16 retired; next stage's stay
        // in flight across the barrier (T4 — never drain to 0 mid-loop).
        if (dc < 7) asm volatile("s_waitcnt vmcnt(8)" ::: "memory");
        else        asm volatile("s_waitcnt vmcnt(0)" ::: "memory");
        __builtin_amdgcn_s_barrier();      // A: all waves' dc tiles visible
        short8 ah[4], al[4], bh[4], bl[4];
#pragma unroll
        for (int i = 0; i < 4; ++i) {
            ah[i] = *(const short8*)&Eh_s[bb][eoffs[i]];
            al[i] = *(const short8*)&El_s[bb][eoffs[i]];
        }
#pragma unroll
        for (int j = 0; j < 4; ++j) {
            bh[j] = *(const short8*)&Xh_s[bb][xoffs[j]];
            bl[j] = *(const short8*)&Xl_s[bb][xoffs[j]];
        }
        __builtin_amdgcn_s_setprio(1);
#pragma unroll
        for (int i = 0; i < 4; ++i)
#pragma unroll
            for (int j = 0; j < 4; ++j) {
                acc[i][j] = __builtin_amdgcn_mfma_f32_16x16x32_bf16(al[i], bh[j], acc[i][j], 0, 0, 0);
                acc[i][j] = __builtin_amdgcn_mfma_f32_16x16x32_bf16(ah[i], bl[j], acc[i][j], 0, 0, 0);
                acc[i][j] = __builtin_amdgcn_mfma_f32_16x16x32_bf16(ah[i], bh[j], acc[i][j], 0, 0, 0);
            }
        __builtin_amdgcn_s_setprio(0);
        __builtin_amdgcn_s_barrier();      // B: all waves done reading buf bb
        if (dc < 6) STAGE(dc + 2, bb);     // overwrite freed buffer
    }

    // Epilogue: per-n top-4 over this block's 128 codes.
    // C layout (16x16): col=lane&15 -> n, row=quad*4+reg -> code.
    Top4 tj[4];
#pragma unroll
    for (int j = 0; j < 4; ++j) {
        const float xxv = xx[n0 + (w & 1) * 64 + j * 16 + lane15];
        Top4 tt; top4_init(tt);
#pragma unroll
        for (int i = 0; i < 4; ++i)
#pragma unroll
            for (int r = 0; r < 4; ++r) {
                const int cl = (w >> 1) * 64 + i * 16 + quad * 4 + r;
                const float t1 = __fadd_rn(xxv, eeLds[cl]);
                const float s = __fmaf_rn(-2.0f, acc[i][j][r], t1);
                top4_insert(tt, s, c0 + cl);
            }
#pragma unroll
        for (int off = 16; off <= 32; off <<= 1) {   // merge quads
            Top4 o;
            o.v0 = __shfl_xor(tt.v0, off, 64); o.i0 = __shfl_xor(tt.i0, off, 64);
            o.v1 = __shfl_xor(tt.v1, off, 64); o.i1 = __shfl_xor(tt.i1, off, 64);
            o.v2 = __shfl_xor(tt.v2, off, 64); o.i2 = __shfl_xor(tt.i2, off, 64);
            o.v3 = __shfl_xor(tt.v3, off, 64);
            top4_merge(tt, o);
        }
        tj[j] = tt;
    }
    __syncthreads();
    if (w >= 2 && quad == 0) {
#pragma unroll
        for (int j = 0; j < 4; ++j) {
            const int idx = (w & 1) * 64 + j * 16 + lane15;
            mV0[idx] = tj[j].v0; mV1[idx] = tj[j].v1; mV2[idx] = tj[j].v2; mV3[idx] = tj[j].v3;
            mI0[idx] = tj[j].i0; mI1[idx] = tj[j].i1; mI2[idx] = tj[j].i2;
        }
    }
    __syncthreads();
    if (w < 2 && quad == 0) {
#pragma unroll
        for (int j = 0; j < 4; ++j) {
            const int idx = w * 64 + j * 16 + lane15;
            Top4 tt = tj[j];
            Top4 o;
            o.v0 = mV0[idx]; o.v1 = mV1[idx]; o.v2 = mV2[idx]; o.v3 = mV3[idx];
            o.i0 = mI0[idx]; o.i1 = mI1[idx]; o.i2 = mI2[idx];
            top4_merge(tt, o);
            mV0[idx] = tt.v0; mV1[idx] = tt.v1; mV2[idx] = tt.v2; mV3[idx] = tt.v3;
            mI0[idx] = tt.i0; mI1[idx] = tt.i1; mI2[idx] = tt.i2;
        }
    }
    __syncthreads();
    // Dense stores: 128 contiguous dwords per array (write-amp fix).
    if (t < 128) {
        const size_t g = (size_t)cblk * NROWS + n0 + t;
        pv0[g] = mV0[t]; pv1[g] = mV1[t]; pv2[g] = mV2[t]; pv3[g] = mV3[t];
        pi0[g] = mI0[t]; pi1[g] = mI1[t]; pi2[g] = mI2[t];
    }
}

// Merge 8 splits: decided rows -> output; ambiguous -> listA (<=24 candidates)
// or listB (a split's v4 within TAU of b1 -> hidden candidate possible).
__global__ void combine_kernel(const float* __restrict__ pv0, const float* __restrict__ pv1,
                               const float* __restrict__ pv2, const float* __restrict__ pv3,
                               const int* __restrict__ pi0, const int* __restrict__ pi1,
                               const int* __restrict__ pi2,
                               int* __restrict__ fidx, float* __restrict__ outIdx,
                               int* __restrict__ counts,
                               int* __restrict__ listA, int* __restrict__ nA,
                               int* __restrict__ listB, int* __restrict__ nB) {
    const int n = blockIdx.x * blockDim.x + threadIdx.x;
    if (n >= NROWS) return;
    float v0[8], v1[8], v2[8]; int i0[8], i1[8], i2[8];
    float b1 = 3.4e38f, v4m = 3.4e38f;
#pragma unroll
    for (int s = 0; s < 8; ++s) {
        const size_t g = (size_t)s * NROWS + n;
        v0[s] = pv0[g]; v1[s] = pv1[g]; v2[s] = pv2[g];
        i0[s] = pi0[g]; i1[s] = pi1[g]; i2[s] = pi2[g];
        b1 = fminf(b1, v0[s]);
        v4m = fminf(v4m, pv3[g]);
    }
    if (v4m - b1 < GAP_TAU) {            // a split may hide a 4th candidate
        const int s = atomicAdd(nB, 1);
        if (s < CAPB) { listB[s] = n; return; }
    } else {
        int ks[24]; int cnt = 0;
#pragma unroll
        for (int s = 0; s < 8; ++s) {
            if (v0[s] - b1 < GAP_TAU) ks[cnt++] = i0[s];
            if (v1[s] - b1 < GAP_TAU) ks[cnt++] = i1[s];
            if (v2[s] - b1 < GAP_TAU) ks[cnt++] = i2[s];
        }
        if (cnt > 1) {
            const int slot = atomicAdd(nA, 1);
            if (slot < CAPA) {
                int* e = listA + (size_t)slot * 32;
                e[0] = n; e[1] = cnt;
                for (int c = 0; c < cnt; ++c) e[2 + c] = ks[c];
                return;
            }
            const int s2 = atomicAdd(nB, 1);       // overflow safety
            if (s2 < CAPB) { listB[s2] = n; return; }
        }
        // cnt == 1: unique within-TAU candidate = true np argmin
        const int bi = ks[0];
        fidx[n] = bi;
        outIdx[n] = (float)bi;
        atomicAdd(&counts[bi], 1);
        return;
    }
    // listB-overflow fallback (never expected): approx winner
    int bi = 0x7fffffff;
#pragma unroll
    for (int s = 0; s < 8; ++s) if (v0[s] == b1 && i0[s] < bi) bi = i0[s];
    fidx[n] = bi; outIdx[n] = (float)bi; atomicAdd(&counts[bi], 1);
}

// Merged resolver. Blocks 0..511: np-exact chain score for listA candidates
// (32 lanes/entry, (s,k)-lexicographic min). Blocks 512..575: full 1024-code
// np-exact rescan for listB rows (safety net, ~0 rows).
__global__ __launch_bounds__(256)
void resolve_kernel(const float* __restrict__ x, const float* __restrict__ emb,
                    const float* __restrict__ ee, const float* __restrict__ xx,
                    const int* __restrict__ listA, const int* __restrict__ nA,
                    const int* __restrict__ listB, const int* __restrict__ nB,
                    int* __restrict__ fidx, float* __restrict__ outIdx,
                    int* __restrict__ counts) {
    __shared__ float xrow[256];
    __shared__ float bV[4];
    __shared__ int   bI[4];
    if (blockIdx.x < 512) {
        int total = *nA; if (total > CAPA) total = CAPA;
        const int sub = threadIdx.x >> 5;
        const int li  = threadIdx.x & 31;
        for (int e = blockIdx.x * 8 + sub; e < total; e += 512 * 8) {
            const int* ent = listA + (size_t)e * 32;
            const int n = ent[0], cnt = ent[1];
            float s = 3.4e38f; int k = 0x7fffffff;
            if (li < cnt) {
                k = ent[2 + li];
                const int b = n >> 10, p = n & 1023;
                const float* xr = x + (size_t)b * 262144 + p;
                const float* er = emb + (size_t)k * 256;
                float dot = 0.f;
#pragma unroll 8
                for (int d = 0; d < 256; ++d)
                    dot = __fmaf_rn(er[d], xr[(size_t)d * 1024], dot);
                s = __fmaf_rn(-2.0f, dot, __fadd_rn(xx[n], ee[k]));
            }
#pragma unroll
            for (int off = 1; off < 32; off <<= 1) {
                const float ov = __shfl_xor(s, off, 32);
                const int   ok = __shfl_xor(k, off, 32);
                if (ov < s || (ov == s && ok < k)) { s = ov; k = ok; }
            }
            if (li == 0) { fidx[n] = k; outIdx[n] = (float)k; atomicAdd(&counts[k], 1); }
        }
        return;
    }
    // rescanB path
    int total = *nB; if (total > CAPB) total = CAPB;
    for (int wq = (int)blockIdx.x - 512; wq < total; wq += 64) {
        const int n = listB[wq];
        const int b = n >> 10, p = n & 1023;
        const float* xb = x + (size_t)b * 262144 + p;
        xrow[threadIdx.x] = xb[(size_t)threadIdx.x * 1024];
        __syncthreads();
        const float xxn = xx[n];
        float best = 3.4e38f; int bi = 0x7fffffff;
        for (int k = threadIdx.x; k < 1024; k += 256) {   // ascending k per thread
            const float* e = emb + (size_t)k * 256;
            float dot = 0.f;
            for (int d = 0; d < 256; ++d) dot = __fmaf_rn(e[d], xrow[d], dot);
            const float t1 = __fadd_rn(xxn, ee[k]);
            const float s = __fmaf_rn(-2.0f, dot, t1);
            if (s < best) { best = s; bi = k; }
        }
        for (int off = 32; off > 0; off >>= 1) {
            const float ov = __shfl_down(best, off, 64);
            const int   oi = __shfl_down(bi,   off, 64);
            if (ov < best || (ov == best && oi < bi)) { best = ov; bi = oi; }
        }
        const int lane = threadIdx.x & 63, wv = threadIdx.x >> 6;
        if (lane == 0) { bV[wv] = best; bI[wv] = bi; }
        __syncthreads();
        if (threadIdx.x == 0) {
            float bb = bV[0]; int ii = bI[0];
            for (int i = 1; i < 4; ++i)
                if (bV[i] < bb || (bV[i] == bb && bI[i] < ii)) { bb = bV[i]; ii = bI[i]; }
            fidx[n] = ii;
            outIdx[n] = (float)ii;
            atomicAdd(&counts[ii], 1);
        }
        __syncthreads();
    }
}

// Quantize: one thread = one pixel x 64 consecutive d. Code row read as
// sequential float4 gathers (each 64B line fetched once); x/out per-d dwords
// coalesced across lanes. tid>>15 = d-chunk, tid&32767 = pixel.
__global__ __launch_bounds__(256)
void quantize_kernel(const float* __restrict__ x, const float* __restrict__ emb,
                     const int* __restrict__ fidx, float* __restrict__ out,
                     float* __restrict__ sumsq) {
    const int tid = blockIdx.x * 256 + threadIdx.x;   // 0..131071
    const int dchunk = tid >> 15;                     // 0..3
    const int n = tid & 32767;
    const int b = n >> 10, p = n & 1023;
    const int d0 = dchunk * 64;
    const int k = fidx[n];
    const float4* er = (const float4*)(emb + (size_t)k * 256 + d0);   // 16 float4
    const float* xr = x + (size_t)b * 262144 + (size_t)d0 * 1024 + p;
    float* orow = out + (size_t)b * 262144 + (size_t)d0 * 1024 + p;
    float loc = 0.f;
#pragma unroll
    for (int j = 0; j < 16; ++j) {
        const float4 qv = er[j];
        const float q[4] = {qv.x, qv.y, qv.z, qv.w};
#pragma unroll
        for (int i = 0; i < 4; ++i) {
            const size_t off = (size_t)(j * 4 + i) * 1024;
            const float xv = xr[off];
            const float e = q[i] - xv;
            orow[off] = xv + e;           // straight-through: x + (q - x)
            loc = fmaf(e, e, loc);
        }
    }
    for (int off = 32; off > 0; off >>= 1) loc += __shfl_down(loc, off, 64);
    __shared__ float red[4];
    const int lane = threadIdx.x & 63, wv = threadIdx.x >> 6;
    if (lane == 0) red[wv] = loc;
    __syncthreads();
    if (threadIdx.x == 0) atomicAdd(sumsq, red[0] + red[1] + red[2] + red[3]);
}

__global__ void finalize_kernel(const int* __restrict__ counts, const float* __restrict__ sumsq,
                                float* __restrict__ outScalars) {
    const int k = threadIdx.x;
    const float p = (float)counts[k] * (1.0f / 32768.0f);
    float term = p * logf(p + 1e-10f);
    for (int off = 32; off > 0; off >>= 1) term += __shfl_down(term, off, 64);
    __shared__ float red[16];
    const int lane = k & 63, wv = k >> 6;
    if (lane == 0) red[wv] = term;
    __syncthreads();
    if (k == 0) {
        float s = 0.f;
        for (int i = 0; i < 16; ++i) s += red[i];
        const float m = sumsq[0] * (1.0f / 8388608.0f);
        outScalars[0] = 1.25f * m;
        outScalars[1] = expf(-s);
    }
}

extern "C" void kernel_launch(void* const* d_in, const int* in_sizes, int n_in,
                              void* d_out, int out_size, void* d_ws, size_t ws_size,
                              hipStream_t stream) {
    const float* x   = (const float*)d_in[0];
    const float* emb = (const float*)d_in[1];
    float* out = (float*)d_out;
    float* W   = (float*)d_ws;
    float* sumsq = W;
    int*   nA    = (int*)(W + 1);
    int*   nB    = (int*)(W + 2);
    int*   counts = (int*)(W + 64);
    float* ee    = W + 1088;
    float* xx    = W + 2112;
    float* pv0   = W + 34880;
    float* pv1   = W + 297024;
    float* pv2   = W + 559168;
    float* pv3   = W + 821312;
    int*   pi0   = (int*)(W + 1083456);
    int*   pi1   = (int*)(W + 1345600);
    int*   pi2   = (int*)(W + 1607744);
    int*   listA = (int*)(W + 1869888);
    int*   listB = (int*)(W + 2394176);
    unsigned short* EhT = (unsigned short*)(W + 2402368);
    unsigned short* ElT = (unsigned short*)(W + 2533440);
    int*   fidx  = (int*)(W + 2664512);
    unsigned short* XhT = (unsigned short*)(W + 2697280);
    unsigned short* XlT = (unsigned short*)(W + 6891584);

    prep_kernel<<<389, 256, 0, stream>>>(emb, x, ee, xx, EhT, ElT, XhT, XlT, W);
    mfma_argmin_kernel<<<2048, 256, 0, stream>>>(XhT, XlT, EhT, ElT, ee, xx,
                                                 pv0, pv1, pv2, pv3, pi0, pi1, pi2);
    combine_kernel<<<128, 256, 0, stream>>>(pv0, pv1, pv2, pv3, pi0, pi1, pi2,
                                            fidx, out + 8388610, counts, listA, nA, listB, nB);
    resolve_kernel<<<576, 256, 0, stream>>>(x, emb, ee, xx, listA, nA, listB, nB,
                                            fidx, out + 8388610, counts);
    quantize_kernel<<<512, 256, 0, stream>>>(x, emb, fidx, out, sumsq);
    finalize_kernel<<<1, 1024, 0, stream>>>(counts, sumsq, out + 8388608);
}

// Round 10
// 226.558 us; speedup vs baseline: 1.0198x; 1.0198x over previous
//
#include <hip/hip_runtime.h>

// VectorQuantizer on MI355X — np-fp32-exact (absmax 0.0). bf16-split MFMA
// approx scores + candidate-exact-compare (np chain) for near-tie rows.
//
// R12: consolidation. Argmin = R10 (best measured total 210.7us; six schedule
// variants R6/R8/R9/R10/R11 bracket the m97-structure ceiling ~792TF — argmin
// is at its structural roofline, reg-bound at 4 waves/SIMD). Gains this round
// target the ~60us of non-argmin slack: (1) prep X-pass 2 threads/pixel (was
// 128 blocks = 2 waves/CU on the 128MB x read; halves split at the np
// pairwise half boundary -> xx = fadd(half0,half1) bit-identical via LDS
// handoff); (2) finalize fused into quantize via last-block-done atomic
// (reduction replicates the original shfl tree bit-exactly); (3) nontemporal
// stores for out (never re-read). 5 dispatches (was 6).
//
// Decision architecture (np-exact guarantees):
//   argmin (MFMA): per-(row,128-code-split) top-4 VALUES + top-3 INDICES
//   combine:       b1 = global best; any split's v4 within TAU of b1 -> listB;
//                  else collect recorded (v,i) with v-b1<TAU: 1 -> decided,
//                  else listA
//   resolve:       listA: np-exact chain per candidate; listB: full rescan
//
// ws layout (float units):
//   0 sumsq | 1 nA | 2 nB | 3 doneCnt | 64 counts[1024] | 1088 ee[1024]
//   2112 xx[32768]
//   34880 pv0 | 297024 pv1 | 559168 pv2 | 821312 pv3            [8*32768 ea]
//   1083456 pi0 | 1345600 pi1 | 1607744 pi2                     [8*32768 ea]
//   1869888 listA[16384*32 int] | 2394176 listB[8192 int]
//   2402368 EhT ushort[262144] | 2533440 ElT ushort[262144]
//   2664512 fidx[32768]
//   2697280 XhT ushort[8*32768*32] | 6891584 XlT ushort[8*32768*32]
//   -> ~44.4 MB total.

#define NROWS 32768
#define CAPA 16384
#define CAPB 8192
#define GAP_TAU 1e-4f

typedef __attribute__((ext_vector_type(8))) short short8;
typedef __attribute__((ext_vector_type(8))) unsigned short ushort8;
typedef __attribute__((ext_vector_type(4))) float f32x4;

// Top-4 values, top-3 indices, value-sorted ascending.
struct Top4 { float v0, v1, v2, v3; int i0, i1, i2; };

__device__ __forceinline__ void top4_init(Top4& t) {
    t.v0 = t.v1 = t.v2 = t.v3 = 3.4e38f;
    t.i0 = t.i1 = t.i2 = 0x7fffffff;
}
__device__ __forceinline__ void top4_insert(Top4& t, float cv, int ci) {
    if (cv < t.v3) {
        if (cv < t.v2) {
            t.v3 = t.v2;
            if (cv < t.v1) {
                t.v2 = t.v1; t.i2 = t.i1;
                if (cv < t.v0) { t.v1 = t.v0; t.i1 = t.i0; t.v0 = cv; t.i0 = ci; }
                else           { t.v1 = cv; t.i1 = ci; }
            } else { t.v2 = cv; t.i2 = ci; }
        } else { t.v3 = cv; }
    }
}
__device__ __forceinline__ void top4_merge(Top4& t, const Top4& o) {
    top4_insert(t, o.v0, o.i0);
    top4_insert(t, o.v1, o.i1);
    top4_insert(t, o.v2, o.i2);
    t.v3 = fminf(t.v3, o.v3);
}

__device__ __forceinline__ unsigned short bf16_rne(float v) {
    unsigned int u = __float_as_uint(v);
    return (unsigned short)((u + 0x7fffu + ((u >> 16) & 1u)) >> 16);
}
__device__ __forceinline__ float bf16_to_f(unsigned short h) {
    return __uint_as_float(((unsigned int)h) << 16);
}

// async global -> LDS, 16B per lane. LDS dest = wave-uniform base + lane*16.
__device__ __forceinline__ void gl16(const void* g, void* l) {
    __builtin_amdgcn_global_load_lds(
        (const __attribute__((address_space(1))) unsigned int*)g,
        (__attribute__((address_space(3))) unsigned int*)l, 16, 0, 0);
}

// numpy pairwise sum of squares over 256: pw128+pw128, 8-lane accumulators.
template <int STRIDE>
__device__ __forceinline__ float np_sumsq256(const float* __restrict__ p) {
    float half[2];
#pragma unroll
    for (int h = 0; h < 2; ++h) {
        float r[8];
#pragma unroll
        for (int j = 0; j < 8; ++j) {
            const float v = p[(size_t)(h * 128 + j) * STRIDE];
            r[j] = __fmul_rn(v, v);
        }
        for (int i = 8; i < 128; i += 8) {
#pragma unroll
            for (int j = 0; j < 8; ++j) {
                const float v = p[(size_t)(h * 128 + i + j) * STRIDE];
                r[j] = __fadd_rn(r[j], __fmul_rn(v, v));
            }
        }
        half[h] = __fadd_rn(__fadd_rn(__fadd_rn(r[0], r[1]), __fadd_rn(r[2], r[3])),
                            __fadd_rn(__fadd_rn(r[4], r[5]), __fadd_rn(r[6], r[7])));
    }
    return __fadd_rn(half[0], half[1]);
}

// blocks 0..3: ee; 4..259: E -> bf16 h/l tiled [dc][code][32] (slot-swizzled);
// 260..515: fused xx + X trunc-split, 2 THREADS PER PIXEL (tid>>7 = half:
// thread h handles dc 4h..4h+3 = one np pairwise half; bit-identical);
// block 516: zero scalars+counts (replaces hipMemsetAsync).
__global__ void prep_kernel(const float* __restrict__ emb, const float* __restrict__ x,
                            float* __restrict__ ee, float* __restrict__ xx,
                            unsigned short* __restrict__ EhT, unsigned short* __restrict__ ElT,
                            unsigned short* __restrict__ XhT, unsigned short* __restrict__ XlT,
                            float* __restrict__ wzero) {
    if (blockIdx.x >= 516) {
        for (int i = threadIdx.x; i < 1088; i += 256) wzero[i] = 0.f;
        return;
    }
    if (blockIdx.x < 4) {
        const int k = blockIdx.x * 256 + threadIdx.x;
        ee[k] = np_sumsq256<1>(emb + (size_t)k * 256);
        return;
    }
    if (blockIdx.x >= 260) {
        // 2 threads per pixel: h = tid>>7 processes dc chunks 4h..4h+3
        // (exactly one pw128 half of the np sum) + that half's X split.
        __shared__ float halfB[128];
        const int pix = threadIdx.x & 127, h = threadIdx.x >> 7;
        const int n = (blockIdx.x - 260) * 128 + pix;
        const int b = n >> 10, p = n & 1023;
        const float* xb = x + (size_t)b * 262144 + p;
        const int kk = (n >> 1) & 3;               // row-in-tile swizzle key
        float r[8];
        float hs = 0.f;
        for (int dq = 0; dq < 4; ++dq) {
            const int dc = h * 4 + dq;
            float v[32];
#pragma unroll
            for (int j = 0; j < 32; ++j)
                v[j] = xb[(size_t)(dc * 32 + j) * 1024];
            // np pairwise accumulation (d-sequential in 8-lane groups)
            if (dq == 0) {
#pragma unroll
                for (int j = 0; j < 8; ++j) r[j] = __fmul_rn(v[j], v[j]);
#pragma unroll
                for (int g = 1; g < 4; ++g)
#pragma unroll
                    for (int j = 0; j < 8; ++j)
                        r[j] = __fadd_rn(r[j], __fmul_rn(v[g * 8 + j], v[g * 8 + j]));
            } else {
#pragma unroll
                for (int g = 0; g < 4; ++g)
#pragma unroll
                    for (int j = 0; j < 8; ++j)
                        r[j] = __fadd_rn(r[j], __fmul_rn(v[g * 8 + j], v[g * 8 + j]));
            }
            if (dq == 3)
                hs = __fadd_rn(
                    __fadd_rn(__fadd_rn(r[0], r[1]), __fadd_rn(r[2], r[3])),
                    __fadd_rn(__fadd_rn(r[4], r[5]), __fadd_rn(r[6], r[7])));
            // truncation split: h = high16(v); l = high16(v - bf16(h)).
            // Store slot g at physical slot g^kk (XOR bank swizzle).
            const size_t xrow = ((size_t)dc * NROWS + n) * 32;
#pragma unroll
            for (int g = 0; g < 4; ++g) {
                ushort8 H, L;
#pragma unroll
                for (int j = 0; j < 8; ++j) {
                    const float vv = v[g * 8 + j];
                    const unsigned int u = __float_as_uint(vv);
                    H[j] = (unsigned short)(u >> 16);
                    const float rr = vv - __uint_as_float(u & 0xFFFF0000u);
                    L[j] = (unsigned short)(__float_as_uint(rr) >> 16);
                }
                *(ushort8*)(XhT + xrow + (g ^ kk) * 8) = H;
                *(ushort8*)(XlT + xrow + (g ^ kk) * 8) = L;
            }
        }
        if (h == 1) halfB[pix] = hs;
        __syncthreads();
        if (h == 0) xx[n] = __fadd_rn(hs, halfB[pix]);   // fl(half0 + half1)
        return;
    }
    // E split (RNE h + RNE residual), tiled [dc][code][32], slot-swizzled.
    const int eid = (blockIdx.x - 4) * 256 + threadIdx.x;   // 0..65535
    const int code = eid >> 6;
    const int d0 = (eid & 63) * 4;
    float4 v = *(const float4*)(emb + (size_t)code * 256 + d0);
    const float vv[4] = {v.x, v.y, v.z, v.w};
    unsigned short h[4], l[4];
#pragma unroll
    for (int i = 0; i < 4; ++i) {
        h[i] = bf16_rne(vv[i]);
        l[i] = bf16_rne(vv[i] - bf16_to_f(h[i]));
    }
    const int kk = (code >> 1) & 3;
    const int slot = (d0 & 31) >> 3;          // 16B slot in 64B row
    const int within = (d0 & 31) & 7;         // ushort offset in slot
    const size_t o = ((size_t)(d0 >> 5) * 1024 + code) * 32
                   + (size_t)((slot ^ kk) * 8 + within);
    *(ushort4*)(EhT + o) = make_ushort4(h[0], h[1], h[2], h[3]);
    *(ushort4*)(ElT + o) = make_ushort4(l[0], l[1], l[2], l[3]);
}

// MFMA argmin: 128 codes x 128 rows per block; grid 2048. R7 decode (natural
// dispatch stagger = inter-block phase diversity). Half-tile phase pipeline:
// P1(dc): stage Eh/Xl[dc], compute al*bh from El/Xh (16 MFMA), barrier;
// P2(dc): stage El/Xh[dc+1], compute ah*bl + ah*bh from Eh/Xl (32 MFMA),
// barrier. Every drain covered by compute. 32KB tiles, 4 blocks/CU.
// 4 waves: w>>1 code-half, w&1 n-half; 4x4 tiles of 16x16x32.
__global__ __launch_bounds__(256, 4)
void mfma_argmin_kernel(const unsigned short* __restrict__ XhT, const unsigned short* __restrict__ XlT,
                        const unsigned short* __restrict__ EhT, const unsigned short* __restrict__ ElT,
                        const float* __restrict__ ee, const float* __restrict__ xx,
                        float* __restrict__ pv0, float* __restrict__ pv1,
                        float* __restrict__ pv2, float* __restrict__ pv3,
                        int* __restrict__ pi0, int* __restrict__ pi1, int* __restrict__ pi2) {
    __shared__ __attribute__((aligned(16))) unsigned short Eh_s[4096];
    __shared__ __attribute__((aligned(16))) unsigned short El_s[4096];
    __shared__ __attribute__((aligned(16))) unsigned short Xh_s[4096];
    __shared__ __attribute__((aligned(16))) unsigned short Xl_s[4096];
    __shared__ float eeLds[128];
    __shared__ float mV0[128], mV1[128], mV2[128], mV3[128];
    __shared__ int   mI0[128], mI1[128], mI2[128];

    const int t = threadIdx.x;
    const int w = t >> 6, lane = t & 63;
    const int lane15 = lane & 15, quad = lane >> 4;
    const int nblk = blockIdx.x & 255, cblk = blockIdx.x >> 8;
    const int n0 = nblk * 128, c0 = cblk * 128;

    if (t < 128) eeLds[t] = ee[c0 + t];

    // Hoisted fragment LDS offsets. Swizzled slot = quad ^ ((lane15>>1)&3)
    // (row bases are multiples of 16 -> key depends only on lane15).
    const int fslot = (quad ^ ((lane15 >> 1) & 3)) * 8;
    int eoffs[4], xoffs[4];
#pragma unroll
    for (int i = 0; i < 4; ++i)
        eoffs[i] = ((w >> 1) * 64 + i * 16 + lane15) * 32 + fslot;
#pragma unroll
    for (int j = 0; j < 4; ++j)
        xoffs[j] = ((w & 1) * 64 + j * 16 + lane15) * 32 + fslot;

    f32x4 acc[4][4];
#pragma unroll
    for (int i = 0; i < 4; ++i)
#pragma unroll
        for (int j = 0; j < 4; ++j) acc[i][j] = (f32x4){0.f, 0.f, 0.f, 0.f};

    // Half-tile stages: A = {El, Xh} (P1 operands), B = {Eh, Xl} (P2).
    auto STAGE_A = [&](int dc) {
        const size_t xoff = ((size_t)dc * NROWS + n0) * 32;
        const size_t eoff = ((size_t)dc * 1024 + c0) * 32;
#pragma unroll
        for (int k = 0; k < 2; ++k) {
            const int id = k * 256 + t;               // 16B chunk index
            const int ldso = (k * 256 + w * 64) * 8;  // wave-uniform ushort off
            gl16(ElT + eoff + (size_t)id * 8, &El_s[ldso]);
            gl16(XhT + xoff + (size_t)id * 8, &Xh_s[ldso]);
        }
    };
    auto STAGE_B = [&](int dc) {
        const size_t xoff = ((size_t)dc * NROWS + n0) * 32;
        const size_t eoff = ((size_t)dc * 1024 + c0) * 32;
#pragma unroll
        for (int k = 0; k < 2; ++k) {
            const int id = k * 256 + t;
            const int ldso = (k * 256 + w * 64) * 8;
            gl16(EhT + eoff + (size_t)id * 8, &Eh_s[ldso]);
            gl16(XlT + xoff + (size_t)id * 8, &Xl_s[ldso]);
        }
    };

    STAGE_A(0);
    __syncthreads();                       // El/Xh[0] ready

    for (int dc = 0; dc < 8; ++dc) {
        // ---- P1: stage B[dc] under 16 MFMAs (al*bh) from A[dc] ----
        STAGE_B(dc);
        short8 al[4], bh[4];
#pragma unroll
        for (int i = 0; i < 4; ++i) al[i] = *(const short8*)&El_s[eoffs[i]];
#pragma unroll
        for (int j = 0; j < 4; ++j) bh[j] = *(const short8*)&Xh_s[xoffs[j]];
#pragma unroll
        for (int i = 0; i < 4; ++i)
#pragma unroll
            for (int j = 0; j < 4; ++j)
                acc[i][j] = __builtin_amdgcn_mfma_f32_16x16x32_bf16(al[i], bh[j], acc[i][j], 0, 0, 0);
        __syncthreads();                   // Eh/Xl[dc] ready; A-reads done
        // ---- P2: stage A[dc+1] under 32 MFMAs (ah*bl, ah*bh) from B[dc] ----
        if (dc < 7) STAGE_A(dc + 1);
        short8 ah[4], bl[4];
#pragma unroll
        for (int i = 0; i < 4; ++i) ah[i] = *(const short8*)&Eh_s[eoffs[i]];
#pragma unroll
        for (int j = 0; j < 4; ++j) bl[j] = *(const short8*)&Xl_s[xoffs[j]];
#pragma unroll
        for (int i = 0; i < 4; ++i)
#pragma unroll
            for (int j = 0; j < 4; ++j)
                acc[i][j] = __builtin_amdgcn_mfma_f32_16x16x32_bf16(ah[i], bl[j], acc[i][j], 0, 0, 0);
#pragma unroll
        for (int i = 0; i < 4; ++i)
#pragma unroll
            for (int j = 0; j < 4; ++j)
                acc[i][j] = __builtin_amdgcn_mfma_f32_16x16x32_bf16(ah[i], bh[j], acc[i][j], 0, 0, 0);
        __syncthreads();                   // El/Xh[dc+1] ready; B-reads done
    }

    // Epilogue: per-n top-4 over this block's 128 codes.
    // C layout (16x16): col=lane&15 -> n, row=quad*4+reg -> code.
    Top4 tj[4];
#pragma unroll
    for (int j = 0; j < 4; ++j) {
        const float xxv = xx[n0 + (w & 1) * 64 + j * 16 + lane15];
        Top4 tt; top4_init(tt);
#pragma unroll
        for (int i = 0; i < 4; ++i)
#pragma unroll
            for (int r = 0; r < 4; ++r) {
                const int cl = (w >> 1) * 64 + i * 16 + quad * 4 + r;
                const float t1 = __fadd_rn(xxv, eeLds[cl]);
                const float s = __fmaf_rn(-2.0f, acc[i][j][r], t1);
                top4_insert(tt, s, c0 + cl);
            }
#pragma unroll
        for (int off = 16; off <= 32; off <<= 1) {   // merge quads
            Top4 o;
            o.v0 = __shfl_xor(tt.v0, off, 64); o.i0 = __shfl_xor(tt.i0, off, 64);
            o.v1 = __shfl_xor(tt.v1, off, 64); o.i1 = __shfl_xor(tt.i1, off, 64);
            o.v2 = __shfl_xor(tt.v2, off, 64); o.i2 = __shfl_xor(tt.i2, off, 64);
            o.v3 = __shfl_xor(tt.v3, off, 64);
            top4_merge(tt, o);
        }
        tj[j] = tt;
    }
    __syncthreads();
    if (w >= 2 && quad == 0) {
#pragma unroll
        for (int j = 0; j < 4; ++j) {
            const int idx = (w & 1) * 64 + j * 16 + lane15;
            mV0[idx] = tj[j].v0; mV1[idx] = tj[j].v1; mV2[idx] = tj[j].v2; mV3[idx] = tj[j].v3;
            mI0[idx] = tj[j].i0; mI1[idx] = tj[j].i1; mI2[idx] = tj[j].i2;
        }
    }
    __syncthreads();
    if (w < 2 && quad == 0) {
#pragma unroll
        for (int j = 0; j < 4; ++j) {
            const int idx = w * 64 + j * 16 + lane15;
            Top4 tt = tj[j];
            Top4 o;
            o.v0 = mV0[idx]; o.v1 = mV1[idx]; o.v2 = mV2[idx]; o.v3 = mV3[idx];
            o.i0 = mI0[idx]; o.i1 = mI1[idx]; o.i2 = mI2[idx];
            top4_merge(tt, o);
            mV0[idx] = tt.v0; mV1[idx] = tt.v1; mV2[idx] = tt.v2; mV3[idx] = tt.v3;
            mI0[idx] = tt.i0; mI1[idx] = tt.i1; mI2[idx] = tt.i2;
        }
    }
    __syncthreads();
    // Dense stores: 128 contiguous dwords per array (write-amp fix).
    if (t < 128) {
        const size_t g = (size_t)cblk * NROWS + n0 + t;
        pv0[g] = mV0[t]; pv1[g] = mV1[t]; pv2[g] = mV2[t]; pv3[g] = mV3[t];
        pi0[g] = mI0[t]; pi1[g] = mI1[t]; pi2[g] = mI2[t];
    }
}

// Merge 8 splits: decided rows -> output; ambiguous -> listA (<=24 candidates)
// or listB (a split's v4 within TAU of b1 -> hidden candidate possible).
__global__ void combine_kernel(const float* __restrict__ pv0, const float* __restrict__ pv1,
                               const float* __restrict__ pv2, const float* __restrict__ pv3,
                               const int* __restrict__ pi0, const int* __restrict__ pi1,
                               const int* __restrict__ pi2,
                               int* __restrict__ fidx, float* __restrict__ outIdx,
                               int* __restrict__ counts,
                               int* __restrict__ listA, int* __restrict__ nA,
                               int* __restrict__ listB, int* __restrict__ nB) {
    const int n = blockIdx.x * blockDim.x + threadIdx.x;
    if (n >= NROWS) return;
    float v0[8], v1[8], v2[8]; int i0[8], i1[8], i2[8];
    float b1 = 3.4e38f, v4m = 3.4e38f;
#pragma unroll
    for (int s = 0; s < 8; ++s) {
        const size_t g = (size_t)s * NROWS + n;
        v0[s] = pv0[g]; v1[s] = pv1[g]; v2[s] = pv2[g];
        i0[s] = pi0[g]; i1[s] = pi1[g]; i2[s] = pi2[g];
        b1 = fminf(b1, v0[s]);
        v4m = fminf(v4m, pv3[g]);
    }
    if (v4m - b1 < GAP_TAU) {            // a split may hide a 4th candidate
        const int s = atomicAdd(nB, 1);
        if (s < CAPB) { listB[s] = n; return; }
    } else {
        int ks[24]; int cnt = 0;
#pragma unroll
        for (int s = 0; s < 8; ++s) {
            if (v0[s] - b1 < GAP_TAU) ks[cnt++] = i0[s];
            if (v1[s] - b1 < GAP_TAU) ks[cnt++] = i1[s];
            if (v2[s] - b1 < GAP_TAU) ks[cnt++] = i2[s];
        }
        if (cnt > 1) {
            const int slot = atomicAdd(nA, 1);
            if (slot < CAPA) {
                int* e = listA + (size_t)slot * 32;
                e[0] = n; e[1] = cnt;
                for (int c = 0; c < cnt; ++c) e[2 + c] = ks[c];
                return;
            }
            const int s2 = atomicAdd(nB, 1);       // overflow safety
            if (s2 < CAPB) { listB[s2] = n; return; }
        }
        // cnt == 1: unique within-TAU candidate = true np argmin
        const int bi = ks[0];
        fidx[n] = bi;
        outIdx[n] = (float)bi;
        atomicAdd(&counts[bi], 1);
        return;
    }
    // listB-overflow fallback (never expected): approx winner
    int bi = 0x7fffffff;
#pragma unroll
    for (int s = 0; s < 8; ++s) if (v0[s] == b1 && i0[s] < bi) bi = i0[s];
    fidx[n] = bi; outIdx[n] = (float)bi; atomicAdd(&counts[bi], 1);
}

// Merged resolver. Blocks 0..511: np-exact chain score for listA candidates
// (32 lanes/entry, (s,k)-lexicographic min). Blocks 512..575: full 1024-code
// np-exact rescan for listB rows (safety net, ~0 rows).
__global__ __launch_bounds__(256)
void resolve_kernel(const float* __restrict__ x, const float* __restrict__ emb,
                    const float* __restrict__ ee, const float* __restrict__ xx,
                    const int* __restrict__ listA, const int* __restrict__ nA,
                    const int* __restrict__ listB, const int* __restrict__ nB,
                    int* __restrict__ fidx, float* __restrict__ outIdx,
                    int* __restrict__ counts) {
    __shared__ float xrow[256];
    __shared__ float bV[4];
    __shared__ int   bI[4];
    if (blockIdx.x < 512) {
        int total = *nA; if (total > CAPA) total = CAPA;
        const int sub = threadIdx.x >> 5;
        const int li  = threadIdx.x & 31;
        for (int e = blockIdx.x * 8 + sub; e < total; e += 512 * 8) {
            const int* ent = listA + (size_t)e * 32;
            const int n = ent[0], cnt = ent[1];
            float s = 3.4e38f; int k = 0x7fffffff;
            if (li < cnt) {
                k = ent[2 + li];
                const int b = n >> 10, p = n & 1023;
                const float* xr = x + (size_t)b * 262144 + p;
                const float* er = emb + (size_t)k * 256;
                float dot = 0.f;
#pragma unroll 8
                for (int d = 0; d < 256; ++d)
                    dot = __fmaf_rn(er[d], xr[(size_t)d * 1024], dot);
                s = __fmaf_rn(-2.0f, dot, __fadd_rn(xx[n], ee[k]));
            }
#pragma unroll
            for (int off = 1; off < 32; off <<= 1) {
                const float ov = __shfl_xor(s, off, 32);
                const int   ok = __shfl_xor(k, off, 32);
                if (ov < s || (ov == s && ok < k)) { s = ov; k = ok; }
            }
            if (li == 0) { fidx[n] = k; outIdx[n] = (float)k; atomicAdd(&counts[k], 1); }
        }
        return;
    }
    // rescanB path
    int total = *nB; if (total > CAPB) total = CAPB;
    for (int wq = (int)blockIdx.x - 512; wq < total; wq += 64) {
        const int n = listB[wq];
        const int b = n >> 10, p = n & 1023;
        const float* xb = x + (size_t)b * 262144 + p;
        xrow[threadIdx.x] = xb[(size_t)threadIdx.x * 1024];
        __syncthreads();
        const float xxn = xx[n];
        float best = 3.4e38f; int bi = 0x7fffffff;
        for (int k = threadIdx.x; k < 1024; k += 256) {   // ascending k per thread
            const float* e = emb + (size_t)k * 256;
            float dot = 0.f;
            for (int d = 0; d < 256; ++d) dot = __fmaf_rn(e[d], xrow[d], dot);
            const float t1 = __fadd_rn(xxn, ee[k]);
            const float s = __fmaf_rn(-2.0f, dot, t1);
            if (s < best) { best = s; bi = k; }
        }
        for (int off = 32; off > 0; off >>= 1) {
            const float ov = __shfl_down(best, off, 64);
            const int   oi = __shfl_down(bi,   off, 64);
            if (ov < best || (ov == best && oi < bi)) { best = ov; bi = oi; }
        }
        const int lane = threadIdx.x & 63, wv = threadIdx.x >> 6;
        if (lane == 0) { bV[wv] = best; bI[wv] = bi; }
        __syncthreads();
        if (threadIdx.x == 0) {
            float bb = bV[0]; int ii = bI[0];
            for (int i = 1; i < 4; ++i)
                if (bV[i] < bb || (bV[i] == bb && bI[i] < ii)) { bb = bV[i]; ii = bI[i]; }
            fidx[n] = ii;
            outIdx[n] = (float)ii;
            atomicAdd(&counts[ii], 1);
        }
        __syncthreads();
    }
}

// Quantize + fused finalize. One thread = one pixel x 64 consecutive d.
// out stores nontemporal (never re-read). Last finished block (doneCnt==511)
// computes loss + perplexity, replicating the original finalize's shfl-tree
// reduction bit-exactly (wave wv handles code-groups wv, wv+4, wv+8, wv+12).
__global__ __launch_bounds__(256)
void quantize_kernel(const float* __restrict__ x, const float* __restrict__ emb,
                     const int* __restrict__ fidx, float* __restrict__ out,
                     float* __restrict__ sumsq, int* __restrict__ doneCnt,
                     const int* __restrict__ counts, float* __restrict__ outScalars) {
    __shared__ float red[16];
    __shared__ int lastFlag;
    const int tid = blockIdx.x * 256 + threadIdx.x;   // 0..131071
    const int dchunk = tid >> 15;                     // 0..3
    const int n = tid & 32767;
    const int b = n >> 10, p = n & 1023;
    const int d0 = dchunk * 64;
    const int k = fidx[n];
    const float4* er = (const float4*)(emb + (size_t)k * 256 + d0);   // 16 float4
    const float* xr = x + (size_t)b * 262144 + (size_t)d0 * 1024 + p;
    float* orow = out + (size_t)b * 262144 + (size_t)d0 * 1024 + p;
    float loc = 0.f;
#pragma unroll
    for (int j = 0; j < 16; ++j) {
        const float4 qv = er[j];
        const float q[4] = {qv.x, qv.y, qv.z, qv.w};
#pragma unroll
        for (int i = 0; i < 4; ++i) {
            const size_t off = (size_t)(j * 4 + i) * 1024;
            const float xv = xr[off];
            const float e = q[i] - xv;
            __builtin_nontemporal_store(xv + e, &orow[off]);  // straight-through
            loc = fmaf(e, e, loc);
        }
    }
    for (int off = 32; off > 0; off >>= 1) loc += __shfl_down(loc, off, 64);
    const int lane = threadIdx.x & 63, wv = threadIdx.x >> 6;
    if (lane == 0) red[wv] = loc;
    __syncthreads();
    if (threadIdx.x == 0) {
        atomicAdd(sumsq, red[0] + red[1] + red[2] + red[3]);
        __threadfence();
        const int d = atomicAdd(doneCnt, 1);
        lastFlag = (d == 511);
    }
    __syncthreads();
    if (!lastFlag) return;
    // ---- fused finalize (last block only) ----
    __threadfence();
    // wave wv computes code-groups g = wv, wv+4, wv+8, wv+12 with the same
    // 64-lane shfl_down tree the standalone finalize used per wave.
#pragma unroll
    for (int gq = 0; gq < 4; ++gq) {
        const int g = wv + gq * 4;
        const int kk = g * 64 + lane;
        const float pr = (float)counts[kk] * (1.0f / 32768.0f);
        float term = pr * logf(pr + 1e-10f);
        for (int off = 32; off > 0; off >>= 1) term += __shfl_down(term, off, 64);
        if (lane == 0) red[g] = term;
    }
    __syncthreads();
    if (threadIdx.x == 0) {
        float s = 0.f;
        for (int i = 0; i < 16; ++i) s += red[i];
        const float sq = atomicAdd(sumsq, 0.0f);     // read total (all adds fenced)
        const float m = sq * (1.0f / 8388608.0f);
        outScalars[0] = 1.25f * m;
        outScalars[1] = expf(-s);
    }
}

extern "C" void kernel_launch(void* const* d_in, const int* in_sizes, int n_in,
                              void* d_out, int out_size, void* d_ws, size_t ws_size,
                              hipStream_t stream) {
    const float* x   = (const float*)d_in[0];
    const float* emb = (const float*)d_in[1];
    float* out = (float*)d_out;
    float* W   = (float*)d_ws;
    float* sumsq = W;
    int*   nA    = (int*)(W + 1);
    int*   nB    = (int*)(W + 2);
    int*   doneCnt = (int*)(W + 3);
    int*   counts = (int*)(W + 64);
    float* ee    = W + 1088;
    float* xx    = W + 2112;
    float* pv0   = W + 34880;
    float* pv1   = W + 297024;
    float* pv2   = W + 559168;
    float* pv3   = W + 821312;
    int*   pi0   = (int*)(W + 1083456);
    int*   pi1   = (int*)(W + 1345600);
    int*   pi2   = (int*)(W + 1607744);
    int*   listA = (int*)(W + 1869888);
    int*   listB = (int*)(W + 2394176);
    unsigned short* EhT = (unsigned short*)(W + 2402368);
    unsigned short* ElT = (unsigned short*)(W + 2533440);
    int*   fidx  = (int*)(W + 2664512);
    unsigned short* XhT = (unsigned short*)(W + 2697280);
    unsigned short* XlT = (unsigned short*)(W + 6891584);

    prep_kernel<<<517, 256, 0, stream>>>(emb, x, ee, xx, EhT, ElT, XhT, XlT, W);
    mfma_argmin_kernel<<<2048, 256, 0, stream>>>(XhT, XlT, EhT, ElT, ee, xx,
                                                 pv0, pv1, pv2, pv3, pi0, pi1, pi2);
    combine_kernel<<<128, 256, 0, stream>>>(pv0, pv1, pv2, pv3, pi0, pi1, pi2,
                                            fidx, out + 8388610, counts, listA, nA, listB, nB);
    resolve_kernel<<<576, 256, 0, stream>>>(x, emb, ee, xx, listA, nA, listB, nB,
                                            fidx, out + 8388610, counts);
    quantize_kernel<<<512, 256, 0, stream>>>(x, emb, fidx, out, sumsq, doneCnt,
                                             counts, out + 8388608);
}

// Round 11
// 204.526 us; speedup vs baseline: 1.1297x; 1.1077x over previous
//
#include <hip/hip_runtime.h>

// VectorQuantizer on MI355X — np-fp32-exact (absmax 0.0). bf16-split MFMA
// approx scores + candidate-exact-compare (np chain) for near-tie rows.
//
// R13: single-variable decomposition of R12's bundle. Base = R10 exactly
// (best measured total 210.7us: half-tile phase-pipelined argmin 64.3us at
// its structural ceiling — six schedule variants bracket it; standalone
// finalize; plain stores). Plus ONLY R12's prep X-pass fix: 2 threads/pixel
// (split at the np pairwise half boundary, xx = fadd(half0,half1) via LDS
// handoff — bit-identical; verified absmax 0.0 in R12), doubling occupancy
// on the 128MB x-read pass. R12's quantize-side changes (NT stores + fused
// finalize with threadfence-after-NT) are dropped as the suspected source
// of its 16us regression.
//
// Decision architecture (np-exact guarantees):
//   argmin (MFMA): per-(row,128-code-split) top-4 VALUES + top-3 INDICES
//   combine:       b1 = global best; any split's v4 within TAU of b1 -> listB;
//                  else collect recorded (v,i) with v-b1<TAU: 1 -> decided,
//                  else listA
//   resolve:       listA: np-exact chain per candidate; listB: full rescan
//
// ws layout (float units):
//   0 sumsq | 1 nA | 2 nB | 64 counts[1024] | 1088 ee[1024] | 2112 xx[32768]
//   34880 pv0 | 297024 pv1 | 559168 pv2 | 821312 pv3            [8*32768 ea]
//   1083456 pi0 | 1345600 pi1 | 1607744 pi2                     [8*32768 ea]
//   1869888 listA[16384*32 int] | 2394176 listB[8192 int]
//   2402368 EhT ushort[262144] | 2533440 ElT ushort[262144]
//   2664512 fidx[32768]
//   2697280 XhT ushort[8*32768*32] | 6891584 XlT ushort[8*32768*32]
//   -> ~44.4 MB total.

#define NROWS 32768
#define CAPA 16384
#define CAPB 8192
#define GAP_TAU 1e-4f

typedef __attribute__((ext_vector_type(8))) short short8;
typedef __attribute__((ext_vector_type(8))) unsigned short ushort8;
typedef __attribute__((ext_vector_type(4))) float f32x4;

// Top-4 values, top-3 indices, value-sorted ascending.
struct Top4 { float v0, v1, v2, v3; int i0, i1, i2; };

__device__ __forceinline__ void top4_init(Top4& t) {
    t.v0 = t.v1 = t.v2 = t.v3 = 3.4e38f;
    t.i0 = t.i1 = t.i2 = 0x7fffffff;
}
__device__ __forceinline__ void top4_insert(Top4& t, float cv, int ci) {
    if (cv < t.v3) {
        if (cv < t.v2) {
            t.v3 = t.v2;
            if (cv < t.v1) {
                t.v2 = t.v1; t.i2 = t.i1;
                if (cv < t.v0) { t.v1 = t.v0; t.i1 = t.i0; t.v0 = cv; t.i0 = ci; }
                else           { t.v1 = cv; t.i1 = ci; }
            } else { t.v2 = cv; t.i2 = ci; }
        } else { t.v3 = cv; }
    }
}
__device__ __forceinline__ void top4_merge(Top4& t, const Top4& o) {
    top4_insert(t, o.v0, o.i0);
    top4_insert(t, o.v1, o.i1);
    top4_insert(t, o.v2, o.i2);
    t.v3 = fminf(t.v3, o.v3);
}

__device__ __forceinline__ unsigned short bf16_rne(float v) {
    unsigned int u = __float_as_uint(v);
    return (unsigned short)((u + 0x7fffu + ((u >> 16) & 1u)) >> 16);
}
__device__ __forceinline__ float bf16_to_f(unsigned short h) {
    return __uint_as_float(((unsigned int)h) << 16);
}

// async global -> LDS, 16B per lane. LDS dest = wave-uniform base + lane*16.
__device__ __forceinline__ void gl16(const void* g, void* l) {
    __builtin_amdgcn_global_load_lds(
        (const __attribute__((address_space(1))) unsigned int*)g,
        (__attribute__((address_space(3))) unsigned int*)l, 16, 0, 0);
}

// numpy pairwise sum of squares over 256: pw128+pw128, 8-lane accumulators.
template <int STRIDE>
__device__ __forceinline__ float np_sumsq256(const float* __restrict__ p) {
    float half[2];
#pragma unroll
    for (int h = 0; h < 2; ++h) {
        float r[8];
#pragma unroll
        for (int j = 0; j < 8; ++j) {
            const float v = p[(size_t)(h * 128 + j) * STRIDE];
            r[j] = __fmul_rn(v, v);
        }
        for (int i = 8; i < 128; i += 8) {
#pragma unroll
            for (int j = 0; j < 8; ++j) {
                const float v = p[(size_t)(h * 128 + i + j) * STRIDE];
                r[j] = __fadd_rn(r[j], __fmul_rn(v, v));
            }
        }
        half[h] = __fadd_rn(__fadd_rn(__fadd_rn(r[0], r[1]), __fadd_rn(r[2], r[3])),
                            __fadd_rn(__fadd_rn(r[4], r[5]), __fadd_rn(r[6], r[7])));
    }
    return __fadd_rn(half[0], half[1]);
}

// blocks 0..3: ee; 4..259: E -> bf16 h/l tiled [dc][code][32] (slot-swizzled);
// 260..515: fused xx + X trunc-split, 2 THREADS PER PIXEL (tid>>7 = half:
// thread h handles dc 4h..4h+3 = one np pairwise half; bit-identical);
// block 516: zero scalars+counts (replaces hipMemsetAsync).
__global__ void prep_kernel(const float* __restrict__ emb, const float* __restrict__ x,
                            float* __restrict__ ee, float* __restrict__ xx,
                            unsigned short* __restrict__ EhT, unsigned short* __restrict__ ElT,
                            unsigned short* __restrict__ XhT, unsigned short* __restrict__ XlT,
                            float* __restrict__ wzero) {
    if (blockIdx.x >= 516) {
        for (int i = threadIdx.x; i < 1088; i += 256) wzero[i] = 0.f;
        return;
    }
    if (blockIdx.x < 4) {
        const int k = blockIdx.x * 256 + threadIdx.x;
        ee[k] = np_sumsq256<1>(emb + (size_t)k * 256);
        return;
    }
    if (blockIdx.x >= 260) {
        // 2 threads per pixel: h = tid>>7 processes dc chunks 4h..4h+3
        // (exactly one pw128 half of the np sum) + that half's X split.
        __shared__ float halfB[128];
        const int pix = threadIdx.x & 127, h = threadIdx.x >> 7;
        const int n = (blockIdx.x - 260) * 128 + pix;
        const int b = n >> 10, p = n & 1023;
        const float* xb = x + (size_t)b * 262144 + p;
        const int kk = (n >> 1) & 3;               // row-in-tile swizzle key
        float r[8];
        float hs = 0.f;
        for (int dq = 0; dq < 4; ++dq) {
            const int dc = h * 4 + dq;
            float v[32];
#pragma unroll
            for (int j = 0; j < 32; ++j)
                v[j] = xb[(size_t)(dc * 32 + j) * 1024];
            // np pairwise accumulation (d-sequential in 8-lane groups)
            if (dq == 0) {
#pragma unroll
                for (int j = 0; j < 8; ++j) r[j] = __fmul_rn(v[j], v[j]);
#pragma unroll
                for (int g = 1; g < 4; ++g)
#pragma unroll
                    for (int j = 0; j < 8; ++j)
                        r[j] = __fadd_rn(r[j], __fmul_rn(v[g * 8 + j], v[g * 8 + j]));
            } else {
#pragma unroll
                for (int g = 0; g < 4; ++g)
#pragma unroll
                    for (int j = 0; j < 8; ++j)
                        r[j] = __fadd_rn(r[j], __fmul_rn(v[g * 8 + j], v[g * 8 + j]));
            }
            if (dq == 3)
                hs = __fadd_rn(
                    __fadd_rn(__fadd_rn(r[0], r[1]), __fadd_rn(r[2], r[3])),
                    __fadd_rn(__fadd_rn(r[4], r[5]), __fadd_rn(r[6], r[7])));
            // truncation split: h = high16(v); l = high16(v - bf16(h)).
            // Store slot g at physical slot g^kk (XOR bank swizzle).
            const size_t xrow = ((size_t)dc * NROWS + n) * 32;
#pragma unroll
            for (int g = 0; g < 4; ++g) {
                ushort8 H, L;
#pragma unroll
                for (int j = 0; j < 8; ++j) {
                    const float vv = v[g * 8 + j];
                    const unsigned int u = __float_as_uint(vv);
                    H[j] = (unsigned short)(u >> 16);
                    const float rr = vv - __uint_as_float(u & 0xFFFF0000u);
                    L[j] = (unsigned short)(__float_as_uint(rr) >> 16);
                }
                *(ushort8*)(XhT + xrow + (g ^ kk) * 8) = H;
                *(ushort8*)(XlT + xrow + (g ^ kk) * 8) = L;
            }
        }
        if (h == 1) halfB[pix] = hs;
        __syncthreads();
        if (h == 0) xx[n] = __fadd_rn(hs, halfB[pix]);   // fl(half0 + half1)
        return;
    }
    // E split (RNE h + RNE residual), tiled [dc][code][32], slot-swizzled.
    const int eid = (blockIdx.x - 4) * 256 + threadIdx.x;   // 0..65535
    const int code = eid >> 6;
    const int d0 = (eid & 63) * 4;
    float4 v = *(const float4*)(emb + (size_t)code * 256 + d0);
    const float vv[4] = {v.x, v.y, v.z, v.w};
    unsigned short h[4], l[4];
#pragma unroll
    for (int i = 0; i < 4; ++i) {
        h[i] = bf16_rne(vv[i]);
        l[i] = bf16_rne(vv[i] - bf16_to_f(h[i]));
    }
    const int kk = (code >> 1) & 3;
    const int slot = (d0 & 31) >> 3;          // 16B slot in 64B row
    const int within = (d0 & 31) & 7;         // ushort offset in slot
    const size_t o = ((size_t)(d0 >> 5) * 1024 + code) * 32
                   + (size_t)((slot ^ kk) * 8 + within);
    *(ushort4*)(EhT + o) = make_ushort4(h[0], h[1], h[2], h[3]);
    *(ushort4*)(ElT + o) = make_ushort4(l[0], l[1], l[2], l[3]);
}

// MFMA argmin: 128 codes x 128 rows per block; grid 2048. R7 decode (natural
// dispatch stagger = inter-block phase diversity). Half-tile phase pipeline:
// P1(dc): stage Eh/Xl[dc], compute al*bh from El/Xh (16 MFMA), barrier;
// P2(dc): stage El/Xh[dc+1], compute ah*bl + ah*bh from Eh/Xl (32 MFMA),
// barrier. Every drain covered by compute. 32KB tiles, 4 blocks/CU.
// 4 waves: w>>1 code-half, w&1 n-half; 4x4 tiles of 16x16x32.
__global__ __launch_bounds__(256, 4)
void mfma_argmin_kernel(const unsigned short* __restrict__ XhT, const unsigned short* __restrict__ XlT,
                        const unsigned short* __restrict__ EhT, const unsigned short* __restrict__ ElT,
                        const float* __restrict__ ee, const float* __restrict__ xx,
                        float* __restrict__ pv0, float* __restrict__ pv1,
                        float* __restrict__ pv2, float* __restrict__ pv3,
                        int* __restrict__ pi0, int* __restrict__ pi1, int* __restrict__ pi2) {
    __shared__ __attribute__((aligned(16))) unsigned short Eh_s[4096];
    __shared__ __attribute__((aligned(16))) unsigned short El_s[4096];
    __shared__ __attribute__((aligned(16))) unsigned short Xh_s[4096];
    __shared__ __attribute__((aligned(16))) unsigned short Xl_s[4096];
    __shared__ float eeLds[128];
    __shared__ float mV0[128], mV1[128], mV2[128], mV3[128];
    __shared__ int   mI0[128], mI1[128], mI2[128];

    const int t = threadIdx.x;
    const int w = t >> 6, lane = t & 63;
    const int lane15 = lane & 15, quad = lane >> 4;
    const int nblk = blockIdx.x & 255, cblk = blockIdx.x >> 8;
    const int n0 = nblk * 128, c0 = cblk * 128;

    if (t < 128) eeLds[t] = ee[c0 + t];

    // Hoisted fragment LDS offsets. Swizzled slot = quad ^ ((lane15>>1)&3)
    // (row bases are multiples of 16 -> key depends only on lane15).
    const int fslot = (quad ^ ((lane15 >> 1) & 3)) * 8;
    int eoffs[4], xoffs[4];
#pragma unroll
    for (int i = 0; i < 4; ++i)
        eoffs[i] = ((w >> 1) * 64 + i * 16 + lane15) * 32 + fslot;
#pragma unroll
    for (int j = 0; j < 4; ++j)
        xoffs[j] = ((w & 1) * 64 + j * 16 + lane15) * 32 + fslot;

    f32x4 acc[4][4];
#pragma unroll
    for (int i = 0; i < 4; ++i)
#pragma unroll
        for (int j = 0; j < 4; ++j) acc[i][j] = (f32x4){0.f, 0.f, 0.f, 0.f};

    // Half-tile stages: A = {El, Xh} (P1 operands), B = {Eh, Xl} (P2).
    auto STAGE_A = [&](int dc) {
        const size_t xoff = ((size_t)dc * NROWS + n0) * 32;
        const size_t eoff = ((size_t)dc * 1024 + c0) * 32;
#pragma unroll
        for (int k = 0; k < 2; ++k) {
            const int id = k * 256 + t;               // 16B chunk index
            const int ldso = (k * 256 + w * 64) * 8;  // wave-uniform ushort off
            gl16(ElT + eoff + (size_t)id * 8, &El_s[ldso]);
            gl16(XhT + xoff + (size_t)id * 8, &Xh_s[ldso]);
        }
    };
    auto STAGE_B = [&](int dc) {
        const size_t xoff = ((size_t)dc * NROWS + n0) * 32;
        const size_t eoff = ((size_t)dc * 1024 + c0) * 32;
#pragma unroll
        for (int k = 0; k < 2; ++k) {
            const int id = k * 256 + t;
            const int ldso = (k * 256 + w * 64) * 8;
            gl16(EhT + eoff + (size_t)id * 8, &Eh_s[ldso]);
            gl16(XlT + xoff + (size_t)id * 8, &Xl_s[ldso]);
        }
    };

    STAGE_A(0);
    __syncthreads();                       // El/Xh[0] ready

    for (int dc = 0; dc < 8; ++dc) {
        // ---- P1: stage B[dc] under 16 MFMAs (al*bh) from A[dc] ----
        STAGE_B(dc);
        short8 al[4], bh[4];
#pragma unroll
        for (int i = 0; i < 4; ++i) al[i] = *(const short8*)&El_s[eoffs[i]];
#pragma unroll
        for (int j = 0; j < 4; ++j) bh[j] = *(const short8*)&Xh_s[xoffs[j]];
#pragma unroll
        for (int i = 0; i < 4; ++i)
#pragma unroll
            for (int j = 0; j < 4; ++j)
                acc[i][j] = __builtin_amdgcn_mfma_f32_16x16x32_bf16(al[i], bh[j], acc[i][j], 0, 0, 0);
        __syncthreads();                   // Eh/Xl[dc] ready; A-reads done
        // ---- P2: stage A[dc+1] under 32 MFMAs (ah*bl, ah*bh) from B[dc] ----
        if (dc < 7) STAGE_A(dc + 1);
        short8 ah[4], bl[4];
#pragma unroll
        for (int i = 0; i < 4; ++i) ah[i] = *(const short8*)&Eh_s[eoffs[i]];
#pragma unroll
        for (int j = 0; j < 4; ++j) bl[j] = *(const short8*)&Xl_s[xoffs[j]];
#pragma unroll
        for (int i = 0; i < 4; ++i)
#pragma unroll
            for (int j = 0; j < 4; ++j)
                acc[i][j] = __builtin_amdgcn_mfma_f32_16x16x32_bf16(ah[i], bl[j], acc[i][j], 0, 0, 0);
#pragma unroll
        for (int i = 0; i < 4; ++i)
#pragma unroll
            for (int j = 0; j < 4; ++j)
                acc[i][j] = __builtin_amdgcn_mfma_f32_16x16x32_bf16(ah[i], bh[j], acc[i][j], 0, 0, 0);
        __syncthreads();                   // El/Xh[dc+1] ready; B-reads done
    }

    // Epilogue: per-n top-4 over this block's 128 codes.
    // C layout (16x16): col=lane&15 -> n, row=quad*4+reg -> code.
    Top4 tj[4];
#pragma unroll
    for (int j = 0; j < 4; ++j) {
        const float xxv = xx[n0 + (w & 1) * 64 + j * 16 + lane15];
        Top4 tt; top4_init(tt);
#pragma unroll
        for (int i = 0; i < 4; ++i)
#pragma unroll
            for (int r = 0; r < 4; ++r) {
                const int cl = (w >> 1) * 64 + i * 16 + quad * 4 + r;
                const float t1 = __fadd_rn(xxv, eeLds[cl]);
                const float s = __fmaf_rn(-2.0f, acc[i][j][r], t1);
                top4_insert(tt, s, c0 + cl);
            }
#pragma unroll
        for (int off = 16; off <= 32; off <<= 1) {   // merge quads
            Top4 o;
            o.v0 = __shfl_xor(tt.v0, off, 64); o.i0 = __shfl_xor(tt.i0, off, 64);
            o.v1 = __shfl_xor(tt.v1, off, 64); o.i1 = __shfl_xor(tt.i1, off, 64);
            o.v2 = __shfl_xor(tt.v2, off, 64); o.i2 = __shfl_xor(tt.i2, off, 64);
            o.v3 = __shfl_xor(tt.v3, off, 64);
            top4_merge(tt, o);
        }
        tj[j] = tt;
    }
    __syncthreads();
    if (w >= 2 && quad == 0) {
#pragma unroll
        for (int j = 0; j < 4; ++j) {
            const int idx = (w & 1) * 64 + j * 16 + lane15;
            mV0[idx] = tj[j].v0; mV1[idx] = tj[j].v1; mV2[idx] = tj[j].v2; mV3[idx] = tj[j].v3;
            mI0[idx] = tj[j].i0; mI1[idx] = tj[j].i1; mI2[idx] = tj[j].i2;
        }
    }
    __syncthreads();
    if (w < 2 && quad == 0) {
#pragma unroll
        for (int j = 0; j < 4; ++j) {
            const int idx = w * 64 + j * 16 + lane15;
            Top4 tt = tj[j];
            Top4 o;
            o.v0 = mV0[idx]; o.v1 = mV1[idx]; o.v2 = mV2[idx]; o.v3 = mV3[idx];
            o.i0 = mI0[idx]; o.i1 = mI1[idx]; o.i2 = mI2[idx];
            top4_merge(tt, o);
            mV0[idx] = tt.v0; mV1[idx] = tt.v1; mV2[idx] = tt.v2; mV3[idx] = tt.v3;
            mI0[idx] = tt.i0; mI1[idx] = tt.i1; mI2[idx] = tt.i2;
        }
    }
    __syncthreads();
    // Dense stores: 128 contiguous dwords per array (write-amp fix).
    if (t < 128) {
        const size_t g = (size_t)cblk * NROWS + n0 + t;
        pv0[g] = mV0[t]; pv1[g] = mV1[t]; pv2[g] = mV2[t]; pv3[g] = mV3[t];
        pi0[g] = mI0[t]; pi1[g] = mI1[t]; pi2[g] = mI2[t];
    }
}

// Merge 8 splits: decided rows -> output; ambiguous -> listA (<=24 candidates)
// or listB (a split's v4 within TAU of b1 -> hidden candidate possible).
__global__ void combine_kernel(const float* __restrict__ pv0, const float* __restrict__ pv1,
                               const float* __restrict__ pv2, const float* __restrict__ pv3,
                               const int* __restrict__ pi0, const int* __restrict__ pi1,
                               const int* __restrict__ pi2,
                               int* __restrict__ fidx, float* __restrict__ outIdx,
                               int* __restrict__ counts,
                               int* __restrict__ listA, int* __restrict__ nA,
                               int* __restrict__ listB, int* __restrict__ nB) {
    const int n = blockIdx.x * blockDim.x + threadIdx.x;
    if (n >= NROWS) return;
    float v0[8], v1[8], v2[8]; int i0[8], i1[8], i2[8];
    float b1 = 3.4e38f, v4m = 3.4e38f;
#pragma unroll
    for (int s = 0; s < 8; ++s) {
        const size_t g = (size_t)s * NROWS + n;
        v0[s] = pv0[g]; v1[s] = pv1[g]; v2[s] = pv2[g];
        i0[s] = pi0[g]; i1[s] = pi1[g]; i2[s] = pi2[g];
        b1 = fminf(b1, v0[s]);
        v4m = fminf(v4m, pv3[g]);
    }
    if (v4m - b1 < GAP_TAU) {            // a split may hide a 4th candidate
        const int s = atomicAdd(nB, 1);
        if (s < CAPB) { listB[s] = n; return; }
    } else {
        int ks[24]; int cnt = 0;
#pragma unroll
        for (int s = 0; s < 8; ++s) {
            if (v0[s] - b1 < GAP_TAU) ks[cnt++] = i0[s];
            if (v1[s] - b1 < GAP_TAU) ks[cnt++] = i1[s];
            if (v2[s] - b1 < GAP_TAU) ks[cnt++] = i2[s];
        }
        if (cnt > 1) {
            const int slot = atomicAdd(nA, 1);
            if (slot < CAPA) {
                int* e = listA + (size_t)slot * 32;
                e[0] = n; e[1] = cnt;
                for (int c = 0; c < cnt; ++c) e[2 + c] = ks[c];
                return;
            }
            const int s2 = atomicAdd(nB, 1);       // overflow safety
            if (s2 < CAPB) { listB[s2] = n; return; }
        }
        // cnt == 1: unique within-TAU candidate = true np argmin
        const int bi = ks[0];
        fidx[n] = bi;
        outIdx[n] = (float)bi;
        atomicAdd(&counts[bi], 1);
        return;
    }
    // listB-overflow fallback (never expected): approx winner
    int bi = 0x7fffffff;
#pragma unroll
    for (int s = 0; s < 8; ++s) if (v0[s] == b1 && i0[s] < bi) bi = i0[s];
    fidx[n] = bi; outIdx[n] = (float)bi; atomicAdd(&counts[bi], 1);
}

// Merged resolver. Blocks 0..511: np-exact chain score for listA candidates
// (32 lanes/entry, (s,k)-lexicographic min). Blocks 512..575: full 1024-code
// np-exact rescan for listB rows (safety net, ~0 rows).
__global__ __launch_bounds__(256)
void resolve_kernel(const float* __restrict__ x, const float* __restrict__ emb,
                    const float* __restrict__ ee, const float* __restrict__ xx,
                    const int* __restrict__ listA, const int* __restrict__ nA,
                    const int* __restrict__ listB, const int* __restrict__ nB,
                    int* __restrict__ fidx, float* __restrict__ outIdx,
                    int* __restrict__ counts) {
    __shared__ float xrow[256];
    __shared__ float bV[4];
    __shared__ int   bI[4];
    if (blockIdx.x < 512) {
        int total = *nA; if (total > CAPA) total = CAPA;
        const int sub = threadIdx.x >> 5;
        const int li  = threadIdx.x & 31;
        for (int e = blockIdx.x * 8 + sub; e < total; e += 512 * 8) {
            const int* ent = listA + (size_t)e * 32;
            const int n = ent[0], cnt = ent[1];
            float s = 3.4e38f; int k = 0x7fffffff;
            if (li < cnt) {
                k = ent[2 + li];
                const int b = n >> 10, p = n & 1023;
                const float* xr = x + (size_t)b * 262144 + p;
                const float* er = emb + (size_t)k * 256;
                float dot = 0.f;
#pragma unroll 8
                for (int d = 0; d < 256; ++d)
                    dot = __fmaf_rn(er[d], xr[(size_t)d * 1024], dot);
                s = __fmaf_rn(-2.0f, dot, __fadd_rn(xx[n], ee[k]));
            }
#pragma unroll
            for (int off = 1; off < 32; off <<= 1) {
                const float ov = __shfl_xor(s, off, 32);
                const int   ok = __shfl_xor(k, off, 32);
                if (ov < s || (ov == s && ok < k)) { s = ov; k = ok; }
            }
            if (li == 0) { fidx[n] = k; outIdx[n] = (float)k; atomicAdd(&counts[k], 1); }
        }
        return;
    }
    // rescanB path
    int total = *nB; if (total > CAPB) total = CAPB;
    for (int wq = (int)blockIdx.x - 512; wq < total; wq += 64) {
        const int n = listB[wq];
        const int b = n >> 10, p = n & 1023;
        const float* xb = x + (size_t)b * 262144 + p;
        xrow[threadIdx.x] = xb[(size_t)threadIdx.x * 1024];
        __syncthreads();
        const float xxn = xx[n];
        float best = 3.4e38f; int bi = 0x7fffffff;
        for (int k = threadIdx.x; k < 1024; k += 256) {   // ascending k per thread
            const float* e = emb + (size_t)k * 256;
            float dot = 0.f;
            for (int d = 0; d < 256; ++d) dot = __fmaf_rn(e[d], xrow[d], dot);
            const float t1 = __fadd_rn(xxn, ee[k]);
            const float s = __fmaf_rn(-2.0f, dot, t1);
            if (s < best) { best = s; bi = k; }
        }
        for (int off = 32; off > 0; off >>= 1) {
            const float ov = __shfl_down(best, off, 64);
            const int   oi = __shfl_down(bi,   off, 64);
            if (ov < best || (ov == best && oi < bi)) { best = ov; bi = oi; }
        }
        const int lane = threadIdx.x & 63, wv = threadIdx.x >> 6;
        if (lane == 0) { bV[wv] = best; bI[wv] = bi; }
        __syncthreads();
        if (threadIdx.x == 0) {
            float bb = bV[0]; int ii = bI[0];
            for (int i = 1; i < 4; ++i)
                if (bV[i] < bb || (bV[i] == bb && bI[i] < ii)) { bb = bV[i]; ii = bI[i]; }
            fidx[n] = ii;
            outIdx[n] = (float)ii;
            atomicAdd(&counts[ii], 1);
        }
        __syncthreads();
    }
}

// Quantize: one thread = one pixel x 64 consecutive d. Code row read as
// sequential float4 gathers (each 64B line fetched once); x/out per-d dwords
// coalesced across lanes. tid>>15 = d-chunk, tid&32767 = pixel.
__global__ __launch_bounds__(256)
void quantize_kernel(const float* __restrict__ x, const float* __restrict__ emb,
                     const int* __restrict__ fidx, float* __restrict__ out,
                     float* __restrict__ sumsq) {
    const int tid = blockIdx.x * 256 + threadIdx.x;   // 0..131071
    const int dchunk = tid >> 15;                     // 0..3
    const int n = tid & 32767;
    const int b = n >> 10, p = n & 1023;
    const int d0 = dchunk * 64;
    const int k = fidx[n];
    const float4* er = (const float4*)(emb + (size_t)k * 256 + d0);   // 16 float4
    const float* xr = x + (size_t)b * 262144 + (size_t)d0 * 1024 + p;
    float* orow = out + (size_t)b * 262144 + (size_t)d0 * 1024 + p;
    float loc = 0.f;
#pragma unroll
    for (int j = 0; j < 16; ++j) {
        const float4 qv = er[j];
        const float q[4] = {qv.x, qv.y, qv.z, qv.w};
#pragma unroll
        for (int i = 0; i < 4; ++i) {
            const size_t off = (size_t)(j * 4 + i) * 1024;
            const float xv = xr[off];
            const float e = q[i] - xv;
            orow[off] = xv + e;           // straight-through: x + (q - x)
            loc = fmaf(e, e, loc);
        }
    }
    for (int off = 32; off > 0; off >>= 1) loc += __shfl_down(loc, off, 64);
    __shared__ float red[4];
    const int lane = threadIdx.x & 63, wv = threadIdx.x >> 6;
    if (lane == 0) red[wv] = loc;
    __syncthreads();
    if (threadIdx.x == 0) atomicAdd(sumsq, red[0] + red[1] + red[2] + red[3]);
}

__global__ void finalize_kernel(const int* __restrict__ counts, const float* __restrict__ sumsq,
                                float* __restrict__ outScalars) {
    const int k = threadIdx.x;
    const float p = (float)counts[k] * (1.0f / 32768.0f);
    float term = p * logf(p + 1e-10f);
    for (int off = 32; off > 0; off >>= 1) term += __shfl_down(term, off, 64);
    __shared__ float red[16];
    const int lane = k & 63, wv = k >> 6;
    if (lane == 0) red[wv] = term;
    __syncthreads();
    if (k == 0) {
        float s = 0.f;
        for (int i = 0; i < 16; ++i) s += red[i];
        const float m = sumsq[0] * (1.0f / 8388608.0f);
        outScalars[0] = 1.25f * m;
        outScalars[1] = expf(-s);
    }
}

extern "C" void kernel_launch(void* const* d_in, const int* in_sizes, int n_in,
                              void* d_out, int out_size, void* d_ws, size_t ws_size,
                              hipStream_t stream) {
    const float* x   = (const float*)d_in[0];
    const float* emb = (const float*)d_in[1];
    float* out = (float*)d_out;
    float* W   = (float*)d_ws;
    float* sumsq = W;
    int*   nA    = (int*)(W + 1);
    int*   nB    = (int*)(W + 2);
    int*   counts = (int*)(W + 64);
    float* ee    = W + 1088;
    float* xx    = W + 2112;
    float* pv0   = W + 34880;
    float* pv1   = W + 297024;
    float* pv2   = W + 559168;
    float* pv3   = W + 821312;
    int*   pi0   = (int*)(W + 1083456);
    int*   pi1   = (int*)(W + 1345600);
    int*   pi2   = (int*)(W + 1607744);
    int*   listA = (int*)(W + 1869888);
    int*   listB = (int*)(W + 2394176);
    unsigned short* EhT = (unsigned short*)(W + 2402368);
    unsigned short* ElT = (unsigned short*)(W + 2533440);
    int*   fidx  = (int*)(W + 2664512);
    unsigned short* XhT = (unsigned short*)(W + 2697280);
    unsigned short* XlT = (unsigned short*)(W + 6891584);

    prep_kernel<<<517, 256, 0, stream>>>(emb, x, ee, xx, EhT, ElT, XhT, XlT, W);
    mfma_argmin_kernel<<<2048, 256, 0, stream>>>(XhT, XlT, EhT, ElT, ee, xx,
                                                 pv0, pv1, pv2, pv3, pi0, pi1, pi2);
    combine_kernel<<<128, 256, 0, stream>>>(pv0, pv1, pv2, pv3, pi0, pi1, pi2,
                                            fidx, out + 8388610, counts, listA, nA, listB, nB);
    resolve_kernel<<<576, 256, 0, stream>>>(x, emb, ee, xx, listA, nA, listB, nB,
                                            fidx, out + 8388610, counts);
    quantize_kernel<<<512, 256, 0, stream>>>(x, emb, fidx, out, sumsq);
    finalize_kernel<<<1, 1024, 0, stream>>>(counts, sumsq, out + 8388608);
}